// Round 8
// baseline (140.269 us; speedup 1.0000x reference)
//
#include <hip/hip_runtime.h>

#define G_ 2048
#define T_ 200

// Output layout (float offsets)
#define OUT_MEANS 0
#define OUT_COVS  3276800     // G*T*S
#define OUT_RS    29491200    // + G*T*S*S
#define OUT_HS    31129600    // + G*T*M*M

// Workspace layout (float offsets)
#define WS_COV 0              // [T][64] cov sequence (row-major 8x8)
#define WS_AB  12800          // [T][80]: A row-major + B^T (b0[8], b1[8])

typedef float f4 __attribute__((ext_vector_type(4)));

// DPP lane permutes (VALU pipe)
#define QP1  0xB1   // lane^1
#define QP2  0x4E   // lane^2
#define HM   0x141  // lane^7 (row_half_mirror)
#define ROR8 0x128  // lane^8 (row_ror:8)

template<int CTRL>
__device__ __forceinline__ float dmov(float x) {
  return __int_as_float(__builtin_amdgcn_update_dpp(
      0, __float_as_int(x), CTRL, 0xF, 0xF, true));
}
template<int OFF>
__device__ __forceinline__ float swzf(float x) {
  return __int_as_float(__builtin_amdgcn_ds_swizzle(__float_as_int(x), OFF));
}

#if __has_builtin(__builtin_amdgcn_permlane16_swap)
#define HAS_PL16 1
#else
#define HAS_PL16 0
#endif
#if __has_builtin(__builtin_amdgcn_permlane32_swap)
#define HAS_PL32 1
#else
#define HAS_PL32 0
#endif

// xor16 / xor32 via permlane*_swap (pure VALU). Builtin returns a 2-elem
// clang vector ([0]=updated old, [1]=updated src); element access only.
// `flip` self-corrects the swap-direction convention (probed vs lane id).
__device__ __forceinline__ float xor16f(float x, int l, bool flip) {
#if HAS_PL16
  auto r = __builtin_amdgcn_permlane16_swap(__float_as_int(x), __float_as_int(x),
                                            false, false);
  const bool sel = (((l & 16) != 0) != flip);
  return __int_as_float(sel ? (int)r[0] : (int)r[1]);
#else
  (void)l; (void)flip;
  return swzf<0x401F>(x);
#endif
}
__device__ __forceinline__ float xor32f(float x, int l, bool flip) {
#if HAS_PL32
  auto r = __builtin_amdgcn_permlane32_swap(__float_as_int(x), __float_as_int(x),
                                            false, false);
  const bool sel = (((l & 32) != 0) != flip);
  return __int_as_float(sel ? (int)r[0] : (int)r[1]);
#else
  (void)l; (void)flip;
  return __shfl_xor(x, 32, 64);
#endif
}

// All 8 row-xor variants: dst[e][lane] = x[lane ^ (e<<3)] — all VALU.
#define ROWVAR(dst, x)                              \
  do {                                              \
    dst[0] = (x);                                   \
    dst[1] = dmov<ROR8>(x);                         \
    dst[2] = xor16f((x), l, flip16);                \
    dst[3] = dmov<ROR8>(dst[2]);                    \
    dst[4] = xor32f((x), l, flip32);                \
    dst[5] = dmov<ROR8>(dst[4]);                    \
    dst[6] = xor16f(dst[4], l, flip16);             \
    dst[7] = dmov<ROR8>(dst[6]);                    \
  } while (0)

__device__ __forceinline__ float rowsum8(float x) {
  x += dmov<QP1>(x); x += dmov<QP2>(x); x += dmov<HM>(x); return x;
}

// ---------------------------------------------------------------------------
// Kernel 1: block 0 = all-VALU Riccati (+ convergence cutoff),
//           blocks 1.. = Rs/Hs broadcast fills
// ---------------------------------------------------------------------------
__global__ void __launch_bounds__(256) k1_riccati_fill(
    const float* __restrict__ F, const float* __restrict__ H,
    const float* __restrict__ Q, const float* __restrict__ R,
    const float* __restrict__ init_cov, float* __restrict__ out,
    float* __restrict__ ws)
{
  if (blockIdx.x == 0) {
    if (threadIdx.x >= 64) return;
    const int l = threadIdx.x;
    const int i = l >> 3, j = l & 7;

    // probe permlane swap direction (self-correcting select)
    bool flip16 = false, flip32 = false;
#if HAS_PL16
    { auto pr = __builtin_amdgcn_permlane16_swap(l, l, false, false);
      const int got = (l & 16) ? (int)pr[0] : (int)pr[1];
      flip16 = (got != (l ^ 16)); }
#endif
#if HAS_PL32
    { auto pr = __builtin_amdgcn_permlane32_swap(l, l, false, false);
      const int got = (l & 32) ? (int)pr[0] : (int)pr[1];
      flip32 = (got != (l ^ 32)); }
#endif

    float c = init_cov[l];                // cov[i][j], shared across groups
    float Hx0[8], Hx1[8], Fix[8], Fjx[8], Fjc[8];
#pragma unroll
    for (int e = 0; e < 8; ++e) {
      const int k = i ^ e;
      Hx0[e] = H[k];
      Hx1[e] = H[8 + k];
      Fix[e] = F[i * 8 + k];
      Fjx[e] = F[j * 8 + k];
      Fjc[e] = F[j * 8 + (j ^ e)];
    }
    const float h0j = H[j], h1j = H[8 + j];
    const float qc  = Q[l];
    const float Fij = F[i * 8 + j];
    const float r00 = R[0], r01 = R[1], r11 = R[3];

    float* __restrict__ covs = ws + WS_COV;
    float* __restrict__ ab   = ws + WS_AB;

    float aL = 0.f, b0L = 0.f, b1L = 0.f;
    int tconv = T_;

    for (int t = 0; t < T_; ++t) {
      covs[t * 64 + l] = c;               // emitted (pre-update) covariance

      float u0 = rowsum8(c * h0j);        // u = c H^T, row-replicated
      float u1 = rowsum8(c * h1j);

      float ue0[8], ue1[8], ce[8];
      ROWVAR(ue0, u0);
      ROWVAR(ue1, u1);
      ROWVAR(ce,  c);

      // S = H c H^T + R, redundantly per lane
      float s00 = r00, s01 = r01, s11 = r11;
#pragma unroll
      for (int e = 0; e < 8; ++e) {
        s00 = fmaf(Hx0[e], ue0[e], s00);
        s01 = fmaf(Hx0[e], ue1[e], s01);
        s11 = fmaf(Hx1[e], ue1[e], s11);
      }
      float det = s00 * s11 - s01 * s01;
      float rd = __builtin_amdgcn_rcpf(det);
      rd = rd * (2.0f - det * rd);
      rd = rd * (2.0f - det * rd);
      const float i00 = s11 * rd, i01 = -s01 * rd, i11 = s00 * rd;

      // G_row = (F c H^T)[i][m]; W = (F c)[i][j]
      float g0 = 0.f, g1 = 0.f, W = 0.f;
#pragma unroll
      for (int e = 0; e < 8; ++e) {
        g0 = fmaf(Fix[e], ue0[e], g0);
        g1 = fmaf(Fix[e], ue1[e], g1);
        W  = fmaf(Fix[e], ce[e],  W);
      }
      const float b0 = fmaf(g0, i00, g1 * i01);   // B = F K
      const float b1 = fmaf(g0, i01, g1 * i11);

      // bG^T[i][j] = sum_e F[j][i^e] * (b . u_e)
      float bGt = 0.f;
#pragma unroll
      for (int e = 0; e < 8; ++e)
        bGt = fmaf(Fjx[e], fmaf(b0, ue0[e], b1 * ue1[e]), bGt);

      // fcf = (F c F^T)[i][j] via column-xor variants of W (all DPP)
      const float w1 = dmov<QP1>(W),  w2 = dmov<QP2>(W), w3 = dmov<QP1>(w2);
      const float w7 = dmov<HM>(W),   w6 = dmov<HM>(w1);
      const float w5 = dmov<HM>(w2),  w4 = dmov<HM>(w3);
      float fcf = Fjc[0] * W;
      fcf = fmaf(Fjc[1], w1, fcf); fcf = fmaf(Fjc[2], w2, fcf);
      fcf = fmaf(Fjc[3], w3, fcf); fcf = fmaf(Fjc[4], w4, fcf);
      fcf = fmaf(Fjc[5], w5, fcf); fcf = fmaf(Fjc[6], w6, fcf);
      fcf = fmaf(Fjc[7], w7, fcf);

      const float cn = fcf + qc - bGt;
      const float A  = Fij - fmaf(b0, h0j, b1 * h1j);

      // A stored ROW-MAJOR: lane (i,j) writes A[i][j] at [i*8+j] = l, so the
      // scan's lane s reads its row A[s][0..7] contiguously at [s*8+k].
      ab[t * 80 + l] = A;
      if (j == 0) { ab[t * 80 + 64 + i] = b0; ab[t * 80 + 72 + i] = b1; }
      aL = A; b0L = b0; b1L = b1;

      const float d = fabsf(cn - c);
      c = cn;
      if (__all(d < 2e-5f)) { tconv = t + 1; break; }
    }
    // steady-state tail fill
    for (int tt = tconv; tt < T_; ++tt) {
      covs[tt * 64 + l] = c;
      ab[tt * 80 + l] = aL;
      if (j == 0) { ab[tt * 80 + 64 + i] = b0L; ab[tt * 80 + 72 + i] = b1L; }
    }
  } else {
    // Rs (1 f4) and Hs (4 f4) broadcast fills
    const f4* __restrict__ R4v = (const f4*)R;
    const f4* __restrict__ H4v = (const f4*)H;
    f4* __restrict__ outRs = (f4*)(out + OUT_RS);
    f4* __restrict__ outHs = (f4*)(out + OUT_HS);
    const int tid = (blockIdx.x - 1) * 256 + threadIdx.x;
    const int str = (gridDim.x - 1) * 256;
    const f4 rv = R4v[0];
    for (int v = tid; v < G_ * T_; v += str)
      __builtin_nontemporal_store(rv, &outRs[v]);
    const f4 hv = H4v[tid & 3];
    for (int v = tid; v < G_ * T_ * 4; v += str)
      __builtin_nontemporal_store(hv, &outHs[v]);
  }
}

// ---------------------------------------------------------------------------
// Kernel 2: blocks 0-63 = mean scan, 8 lanes per group (lane s owns m[s]);
//           blocks 64.. = covs broadcast fill
// ---------------------------------------------------------------------------
__global__ void __launch_bounds__(256, 1) k2_scan_fill(
    const float* __restrict__ input, const float* __restrict__ init_mean,
    const float* __restrict__ ws, float* __restrict__ out)
{
  if (blockIdx.x < 64) {
    const int s = threadIdx.x & 7;
    const int g = blockIdx.x * 32 + (threadIdx.x >> 3);

    const float* __restrict__ abf = ws + WS_AB;   // [T][80]
    const f4* __restrict__ abf4 = (const f4*)abf;
    const float2* __restrict__ inp2 = (const float2*)input;  // [G*T]
    float* __restrict__ outm = out + OUT_MEANS;

    float m = init_mean[g * 8 + s];

    // row s of A lives at abf[t*80 + s*8 + k], k=0..7 (contiguous)
    f4 a0 = abf4[s * 2], a1 = abf4[s * 2 + 1];
    float b0 = abf[64 + s], b1 = abf[72 + s];
    float2 y = inp2[g * T_];

    for (int t = 0; t < T_; ++t) {
      const int tn = (t + 1 < T_) ? t + 1 : t;
      // prefetch t+1 (independent of m)
      const f4 a0n = abf4[tn * 20 + s * 2];
      const f4 a1n = abf4[tn * 20 + s * 2 + 1];
      const float b0n = abf[tn * 80 + 64 + s];
      const float b1n = abf[tn * 80 + 72 + s];
      const float2 yn = inp2[g * T_ + tn];

      outm[g * (T_ * 8) + t * 8 + s] = m;   // emit pre-update mean

      // broadcast m[k] within the 8-lane group: and-mask keeps bits 3-4
      const float M0 = swzf<(0 << 5) | 0x18>(m);
      const float M1 = swzf<(1 << 5) | 0x18>(m);
      const float M2 = swzf<(2 << 5) | 0x18>(m);
      const float M3 = swzf<(3 << 5) | 0x18>(m);
      const float M4 = swzf<(4 << 5) | 0x18>(m);
      const float M5 = swzf<(5 << 5) | 0x18>(m);
      const float M6 = swzf<(6 << 5) | 0x18>(m);
      const float M7 = swzf<(7 << 5) | 0x18>(m);

      const float u0 = fmaf(a0.x, M0, a0.y * M1);
      const float u1 = fmaf(a0.z, M2, a0.w * M3);
      const float u2 = fmaf(a1.x, M4, a1.y * M5);
      const float u3 = fmaf(a1.z, M6, a1.w * M7);
      const float u4 = fmaf(b0, y.x, b1 * y.y);
      m = (u0 + u1) + ((u2 + u3) + u4);

      a0 = a0n; a1 = a1n; b0 = b0n; b1 = b1n; y = yn;
    }
  } else {
    // covs fill: one ws-read/thread, g-loop of coalesced nontemporal stores
    const int fb  = blockIdx.x - 64;
    const int t16 = fb % 13;
    const int gsl = fb / 13;
    const int t   = t16 * 16 + (threadIdx.x >> 4);
    const int e4  = threadIdx.x & 15;
    if (t >= T_) return;
    const f4* __restrict__ cov4 = (const f4*)(ws + WS_COV); // [T][16]
    f4* __restrict__ outc = (f4*)(out + OUT_COVS);
    const f4 val = cov4[t * 16 + e4];
    const int g0 = gsl * 32;
#pragma unroll 4
    for (int g = g0; g < g0 + 32; ++g)
      __builtin_nontemporal_store(val, &outc[(g * T_ + t) * 16 + e4]);
  }
}

extern "C" void kernel_launch(void* const* d_in, const int* in_sizes, int n_in,
                              void* d_out, int out_size, void* d_ws, size_t ws_size,
                              hipStream_t stream) {
  const float* input     = (const float*)d_in[0];
  const float* F         = (const float*)d_in[1];
  const float* H         = (const float*)d_in[2];
  const float* Q         = (const float*)d_in[3];
  const float* R         = (const float*)d_in[4];
  const float* init_mean = (const float*)d_in[5];
  const float* init_cov  = (const float*)d_in[6];
  float* out = (float*)d_out;
  float* ws  = (float*)d_ws;

  k1_riccati_fill<<<513, 256, 0, stream>>>(F, H, Q, R, init_cov, out, ws);
  k2_scan_fill<<<64 + 13 * 64, 256, 0, stream>>>(input, init_mean, ws, out);
}

// Round 9
// 139.147 us; speedup vs baseline: 1.0081x; 1.0081x over previous
//
#include <hip/hip_runtime.h>

#define G_ 2048
#define T_ 200

// Output layout (float offsets)
#define OUT_MEANS 0
#define OUT_COVS  3276800     // G*T*S
#define OUT_RS    29491200    // + G*T*S*S
#define OUT_HS    31129600    // + G*T*M*M

// Workspace layout (float offsets)
#define WS_COV 0              // [T][64] cov sequence (row-major 8x8)
#define WS_AB  12800          // [T][80]: A in XOR layout ([s][e] = A[s][s^e]) + b0[8], b1[8]

typedef float f4 __attribute__((ext_vector_type(4)));

// DPP lane permutes (VALU pipe)
#define QP1  0xB1   // lane^1 (quad_perm [1,0,3,2])
#define QP2  0x4E   // lane^2 (quad_perm [2,3,0,1])
#define HM   0x141  // lane^7 within each 8 (row_half_mirror)
#define ROR8 0x128  // lane^8 within 16 (row_ror:8)

template<int CTRL>
__device__ __forceinline__ float dmov(float x) {
  return __int_as_float(__builtin_amdgcn_update_dpp(
      0, __float_as_int(x), CTRL, 0xF, 0xF, true));
}
template<int OFF>
__device__ __forceinline__ float swzf(float x) {
  return __int_as_float(__builtin_amdgcn_ds_swizzle(__float_as_int(x), OFF));
}

#if __has_builtin(__builtin_amdgcn_permlane16_swap)
#define HAS_PL16 1
#else
#define HAS_PL16 0
#endif
#if __has_builtin(__builtin_amdgcn_permlane32_swap)
#define HAS_PL32 1
#else
#define HAS_PL32 0
#endif

__device__ __forceinline__ float xor16f(float x, int l, bool flip) {
#if HAS_PL16
  auto r = __builtin_amdgcn_permlane16_swap(__float_as_int(x), __float_as_int(x),
                                            false, false);
  const bool sel = (((l & 16) != 0) != flip);
  return __int_as_float(sel ? (int)r[0] : (int)r[1]);
#else
  (void)l; (void)flip;
  return swzf<0x401F>(x);
#endif
}
__device__ __forceinline__ float xor32f(float x, int l, bool flip) {
#if HAS_PL32
  auto r = __builtin_amdgcn_permlane32_swap(__float_as_int(x), __float_as_int(x),
                                            false, false);
  const bool sel = (((l & 32) != 0) != flip);
  return __int_as_float(sel ? (int)r[0] : (int)r[1]);
#else
  (void)l; (void)flip;
  return __shfl_xor(x, 32, 64);
#endif
}

// All 8 row-xor variants: dst[e][lane] = x[lane ^ (e<<3)] — all VALU.
#define ROWVAR(dst, x)                              \
  do {                                              \
    dst[0] = (x);                                   \
    dst[1] = dmov<ROR8>(x);                         \
    dst[2] = xor16f((x), l, flip16);                \
    dst[3] = dmov<ROR8>(dst[2]);                    \
    dst[4] = xor32f((x), l, flip32);                \
    dst[5] = dmov<ROR8>(dst[4]);                    \
    dst[6] = xor16f(dst[4], l, flip16);             \
    dst[7] = dmov<ROR8>(dst[6]);                    \
  } while (0)

__device__ __forceinline__ float rowsum8(float x) {
  x += dmov<QP1>(x); x += dmov<QP2>(x); x += dmov<HM>(x); return x;
}

// depth-4 tree dot of 8 coefficient*variant products
#define DOT8(res, C, V)                                          \
  do {                                                           \
    const float t0_ = fmaf(C[0], V[0], C[1] * V[1]);             \
    const float t1_ = fmaf(C[2], V[2], C[3] * V[3]);             \
    const float t2_ = fmaf(C[4], V[4], C[5] * V[5]);             \
    const float t3_ = fmaf(C[6], V[6], C[7] * V[7]);             \
    res = (t0_ + t1_) + (t2_ + t3_);                             \
  } while (0)

// ---------------------------------------------------------------------------
// Kernel 1: block 0 = tree-FMA all-VALU Riccati (+ periodic cutoff),
//           blocks 1.. = Rs/Hs broadcast fills
// ---------------------------------------------------------------------------
__global__ void __launch_bounds__(256) k1_riccati_fill(
    const float* __restrict__ F, const float* __restrict__ H,
    const float* __restrict__ Q, const float* __restrict__ R,
    const float* __restrict__ init_cov, float* __restrict__ out,
    float* __restrict__ ws)
{
  if (blockIdx.x == 0) {
    if (threadIdx.x >= 64) return;
    const int l = threadIdx.x;
    const int i = l >> 3, j = l & 7;

    bool flip16 = false, flip32 = false;
#if HAS_PL16
    { auto pr = __builtin_amdgcn_permlane16_swap(l, l, false, false);
      const int got = (l & 16) ? (int)pr[0] : (int)pr[1];
      flip16 = (got != (l ^ 16)); }
#endif
#if HAS_PL32
    { auto pr = __builtin_amdgcn_permlane32_swap(l, l, false, false);
      const int got = (l & 32) ? (int)pr[0] : (int)pr[1];
      flip32 = (got != (l ^ 32)); }
#endif

    float c = init_cov[l];                // cov[i][j], shared across groups
    float Hx0[8], Hx1[8], Fix[8], Fjx[8], Fjc[8];
#pragma unroll
    for (int e = 0; e < 8; ++e) {
      const int k = i ^ e;
      Hx0[e] = H[k];
      Hx1[e] = H[8 + k];
      Fix[e] = F[i * 8 + k];
      Fjx[e] = F[j * 8 + k];
      Fjc[e] = F[j * 8 + (j ^ e)];
    }
    const float h0j = H[j], h1j = H[8 + j];
    const float qc  = Q[l];
    const float Fij = F[i * 8 + j];
    const float r00 = R[0], r01 = R[1], r11 = R[3];

    float* __restrict__ covs = ws + WS_COV;
    float* __restrict__ ab   = ws + WS_AB;
    const int axaddr = (i << 3) + (i ^ j);  // XOR-layout address for A

    float aL = 0.f, b0L = 0.f, b1L = 0.f;
    int tconv = T_;

    for (int t = 0; t < T_; ++t) {
      covs[t * 64 + l] = c;               // emitted (pre-update) covariance

      float u0 = rowsum8(c * h0j);        // u = c H^T, row-replicated
      float u1 = rowsum8(c * h1j);

      float ue0[8], ue1[8], ce[8];
      ROWVAR(ue0, u0);
      ROWVAR(ue1, u1);
      ROWVAR(ce,  c);

      // S = H c H^T + R (per-lane redundant), tree-FMA
      float s00, s01, s11;
      DOT8(s00, Hx0, ue0); s00 += r00;
      DOT8(s01, Hx0, ue1); s01 += r01;
      DOT8(s11, Hx1, ue1); s11 += r11;
      float det = s00 * s11 - s01 * s01;
      float rd = __builtin_amdgcn_rcpf(det);
      rd = rd * (2.0f - det * rd);
      rd = rd * (2.0f - det * rd);
      const float i00 = s11 * rd, i01 = -s01 * rd, i11 = s00 * rd;

      // G_row = (F c H^T)[i][m]; W = (F c)[i][j]
      float g0, g1, W;
      DOT8(g0, Fix, ue0);
      DOT8(g1, Fix, ue1);
      DOT8(W,  Fix, ce);
      const float b0 = fmaf(g0, i00, g1 * i01);   // B = F K
      const float b1 = fmaf(g0, i01, g1 * i11);

      // bG^T[i][j] = sum_e F[j][i^e] * (b . u_e), tree
      float bu[8];
#pragma unroll
      for (int e = 0; e < 8; ++e) bu[e] = fmaf(b0, ue0[e], b1 * ue1[e]);
      float bGt;
      DOT8(bGt, Fjx, bu);

      // fcf = (F c F^T)[i][j] via column-xor variants of W (all DPP), tree
      float wv[8];
      wv[0] = W;
      wv[1] = dmov<QP1>(W);
      wv[2] = dmov<QP2>(W);
      wv[3] = dmov<QP1>(wv[2]);
      wv[7] = dmov<HM>(W);
      wv[6] = dmov<HM>(wv[1]);
      wv[5] = dmov<HM>(wv[2]);
      wv[4] = dmov<HM>(wv[3]);
      float fcf;
      DOT8(fcf, Fjc, wv);

      const float cn = fcf + qc - bGt;
      const float A  = Fij - fmaf(b0, h0j, b1 * h1j);

      // A stored in XOR layout: lane (i,j) writes A[i][j] at [i*8 + (i^j)],
      // so scan lane s reads ae[e] = A[s][s^e] contiguously at [s*8+e].
      ab[t * 80 + axaddr] = A;
      if (j == 0) { ab[t * 80 + 64 + i] = b0; ab[t * 80 + 72 + i] = b1; }
      aL = A; b0L = b0; b1L = b1;

      const float d = fabsf(cn - c);
      c = cn;
      // cheap certain cutoff: test only every 8th step once decayed
      if ((t & 7) == 7 && t >= 95) {
        if (__all(d < 3e-5f)) { tconv = t + 1; break; }
      }
    }
    // steady-state tail fill
    for (int tt = tconv; tt < T_; ++tt) {
      covs[tt * 64 + l] = c;
      ab[tt * 80 + axaddr] = aL;
      if (j == 0) { ab[tt * 80 + 64 + i] = b0L; ab[tt * 80 + 72 + i] = b1L; }
    }
  } else {
    // Rs (1 f4) and Hs (4 f4) broadcast fills
    const f4* __restrict__ R4v = (const f4*)R;
    const f4* __restrict__ H4v = (const f4*)H;
    f4* __restrict__ outRs = (f4*)(out + OUT_RS);
    f4* __restrict__ outHs = (f4*)(out + OUT_HS);
    const int tid = (blockIdx.x - 1) * 256 + threadIdx.x;
    const int str = (gridDim.x - 1) * 256;
    const f4 rv = R4v[0];
    for (int v = tid; v < G_ * T_; v += str)
      __builtin_nontemporal_store(rv, &outRs[v]);
    const f4 hv = H4v[tid & 3];
    for (int v = tid; v < G_ * T_ * 4; v += str)
      __builtin_nontemporal_store(hv, &outHs[v]);
  }
}

// ---------------------------------------------------------------------------
// Kernel 2: blocks 0-63 = mean scan, 8 lanes/group, all-DPP broadcasts;
//           blocks 64.. = covs broadcast fill
// ---------------------------------------------------------------------------
__global__ void __launch_bounds__(256, 1) k2_scan_fill(
    const float* __restrict__ input, const float* __restrict__ init_mean,
    const float* __restrict__ ws, float* __restrict__ out)
{
  if (blockIdx.x < 64) {
    const int s = threadIdx.x & 7;
    const int g = blockIdx.x * 32 + (threadIdx.x >> 3);

    const float* __restrict__ abf = ws + WS_AB;   // [T][80], A in XOR layout
    const f4* __restrict__ abf4 = (const f4*)abf;
    const float2* __restrict__ inp2 = (const float2*)input;  // [G*T]
    float* __restrict__ outm = out + OUT_MEANS;

    float m = init_mean[g * 8 + s];

    // ae[e] = A[s][s^e] at abf[t*80 + s*8 + e]
    f4 a0 = abf4[s * 2], a1 = abf4[s * 2 + 1];
    float b0 = abf[64 + s], b1 = abf[72 + s];
    float2 y = inp2[g * T_];

    for (int t = 0; t < T_; ++t) {
      const int tn = (t + 1 < T_) ? t + 1 : t;
      // prefetch t+1 (independent of m)
      const f4 a0n = abf4[tn * 20 + s * 2];
      const f4 a1n = abf4[tn * 20 + s * 2 + 1];
      const float b0n = abf[tn * 80 + 64 + s];
      const float b1n = abf[tn * 80 + 72 + s];
      const float2 yn = inp2[g * T_ + tn];

      outm[g * (T_ * 8) + t * 8 + s] = m;   // emit pre-update mean

      // group-local xor variants of m: M[e] = m[s^e] — pure DPP
      const float M1 = dmov<QP1>(m);
      const float M2 = dmov<QP2>(m);
      const float M3 = dmov<QP1>(M2);
      const float M7 = dmov<HM>(m);
      const float M6 = dmov<HM>(M1);
      const float M5 = dmov<HM>(M2);
      const float M4 = dmov<HM>(M3);

      const float p0 = fmaf(a0.x, m,  a0.y * M1);
      const float p1 = fmaf(a0.z, M2, a0.w * M3);
      const float p2 = fmaf(a1.x, M4, a1.y * M5);
      const float p3 = fmaf(a1.z, M6, a1.w * M7);
      const float py = fmaf(b0, y.x, b1 * y.y);
      m = ((p0 + p1) + (p2 + p3)) + py;

      a0 = a0n; a1 = a1n; b0 = b0n; b1 = b1n; y = yn;
    }
  } else {
    // covs fill: one ws-read/thread, g-loop of coalesced nontemporal stores
    const int fb  = blockIdx.x - 64;
    const int t16 = fb % 13;
    const int gsl = fb / 13;
    const int t   = t16 * 16 + (threadIdx.x >> 4);
    const int e4  = threadIdx.x & 15;
    if (t >= T_) return;
    const f4* __restrict__ cov4 = (const f4*)(ws + WS_COV); // [T][16]
    f4* __restrict__ outc = (f4*)(out + OUT_COVS);
    const f4 val = cov4[t * 16 + e4];
    const int g0 = gsl * 32;
#pragma unroll 4
    for (int g = g0; g < g0 + 32; ++g)
      __builtin_nontemporal_store(val, &outc[(g * T_ + t) * 16 + e4]);
  }
}

extern "C" void kernel_launch(void* const* d_in, const int* in_sizes, int n_in,
                              void* d_out, int out_size, void* d_ws, size_t ws_size,
                              hipStream_t stream) {
  const float* input     = (const float*)d_in[0];
  const float* F         = (const float*)d_in[1];
  const float* H         = (const float*)d_in[2];
  const float* Q         = (const float*)d_in[3];
  const float* R         = (const float*)d_in[4];
  const float* init_mean = (const float*)d_in[5];
  const float* init_cov  = (const float*)d_in[6];
  float* out = (float*)d_out;
  float* ws  = (float*)d_ws;

  k1_riccati_fill<<<513, 256, 0, stream>>>(F, H, Q, R, init_cov, out, ws);
  k2_scan_fill<<<64 + 13 * 64, 256, 0, stream>>>(input, init_mean, ws, out);
}

// Round 10
// 76.751 us; speedup vs baseline: 1.8276x; 1.8130x over previous
//
#include <hip/hip_runtime.h>

#define G_ 2048
#define T_ 200

// Output layout (float offsets)
#define OUT_MEANS 0
#define OUT_COVS  3276800     // G*T*S
#define OUT_RS    29491200    // + G*T*S*S
#define OUT_HS    31129600    // + G*T*M*M

// Workspace layout (float offsets)
#define WS_AB   0             // [T][80]: A in XOR layout + b0[8], b1[8]
#define WS_FLAG 16000         // one uint flag (after the A/B table)
#define MAGIC   0x5CA1AB1Eu

typedef float f4 __attribute__((ext_vector_type(4)));

// DPP lane permutes (VALU pipe)
#define QP1  0xB1   // lane^1
#define QP2  0x4E   // lane^2
#define HM   0x141  // lane^7 (row_half_mirror)
#define ROR8 0x128  // lane^8 (row_ror:8)

template<int CTRL>
__device__ __forceinline__ float dmov(float x) {
  return __int_as_float(__builtin_amdgcn_update_dpp(
      0, __float_as_int(x), CTRL, 0xF, 0xF, true));
}
template<int OFF>
__device__ __forceinline__ float swzf(float x) {
  return __int_as_float(__builtin_amdgcn_ds_swizzle(__float_as_int(x), OFF));
}

#if __has_builtin(__builtin_amdgcn_permlane16_swap)
#define HAS_PL16 1
#else
#define HAS_PL16 0
#endif
#if __has_builtin(__builtin_amdgcn_permlane32_swap)
#define HAS_PL32 1
#else
#define HAS_PL32 0
#endif

__device__ __forceinline__ float xor16f(float x, int l, bool flip) {
#if HAS_PL16
  auto r = __builtin_amdgcn_permlane16_swap(__float_as_int(x), __float_as_int(x),
                                            false, false);
  const bool sel = (((l & 16) != 0) != flip);
  return __int_as_float(sel ? (int)r[0] : (int)r[1]);
#else
  (void)l; (void)flip;
  return swzf<0x401F>(x);
#endif
}
__device__ __forceinline__ float xor32f(float x, int l, bool flip) {
#if HAS_PL32
  auto r = __builtin_amdgcn_permlane32_swap(__float_as_int(x), __float_as_int(x),
                                            false, false);
  const bool sel = (((l & 32) != 0) != flip);
  return __int_as_float(sel ? (int)r[0] : (int)r[1]);
#else
  (void)l; (void)flip;
  return __shfl_xor(x, 32, 64);
#endif
}

// All 8 row-xor variants: dst[e][lane] = x[lane ^ (e<<3)] — all VALU.
#define ROWVAR(dst, x)                              \
  do {                                              \
    dst[0] = (x);                                   \
    dst[1] = dmov<ROR8>(x);                         \
    dst[2] = xor16f((x), l, flip16);                \
    dst[3] = dmov<ROR8>(dst[2]);                    \
    dst[4] = xor32f((x), l, flip32);                \
    dst[5] = dmov<ROR8>(dst[4]);                    \
    dst[6] = xor16f(dst[4], l, flip16);             \
    dst[7] = dmov<ROR8>(dst[6]);                    \
  } while (0)

__device__ __forceinline__ float rowsum8(float x) {
  x += dmov<QP1>(x); x += dmov<QP2>(x); x += dmov<HM>(x); return x;
}

#define DOT8(res, C, V)                                          \
  do {                                                           \
    const float t0_ = fmaf(C[0], V[0], C[1] * V[1]);             \
    const float t1_ = fmaf(C[2], V[2], C[3] * V[3]);             \
    const float t2_ = fmaf(C[4], V[4], C[5] * V[5]);             \
    const float t3_ = fmaf(C[6], V[6], C[7] * V[7]);             \
    res = (t0_ + t1_) + (t2_ + t3_);                             \
  } while (0)

__device__ __forceinline__ void wait_flag(const unsigned* flag) {
  if (threadIdx.x == 0) {
    while (__hip_atomic_load(flag, __ATOMIC_ACQUIRE,
                             __HIP_MEMORY_SCOPE_AGENT) != MAGIC)
      __builtin_amdgcn_s_sleep(2);
  }
  __syncthreads();
}

// ---------------------------------------------------------------------------
// Fused kernel:
//   block 0       : Riccati (covs -> out g=0 slot, A/B -> ws), release flag
//   blocks 1-64   : Rs fill, wait flag, 8-lane-per-group mean scan
//   blocks 65-1026: Hs fill, wait flag, covs broadcast fill (g=1..2047)
// ---------------------------------------------------------------------------
__global__ void __launch_bounds__(256, 1) kfused(
    const float* __restrict__ input, const float* __restrict__ F,
    const float* __restrict__ H, const float* __restrict__ Q,
    const float* __restrict__ R, const float* __restrict__ init_mean,
    const float* __restrict__ init_cov, float* __restrict__ out,
    float* __restrict__ ws)
{
  const int bid = blockIdx.x;
  float* __restrict__ ab = ws + WS_AB;
  unsigned* flag = (unsigned*)(ws + WS_FLAG);

  if (bid == 0) {
    if (threadIdx.x >= 64) return;
    const int l = threadIdx.x;
    const int i = l >> 3, j = l & 7;

    bool flip16 = false, flip32 = false;
#if HAS_PL16
    { auto pr = __builtin_amdgcn_permlane16_swap(l, l, false, false);
      const int got = (l & 16) ? (int)pr[0] : (int)pr[1];
      flip16 = (got != (l ^ 16)); }
#endif
#if HAS_PL32
    { auto pr = __builtin_amdgcn_permlane32_swap(l, l, false, false);
      const int got = (l & 32) ? (int)pr[0] : (int)pr[1];
      flip32 = (got != (l ^ 32)); }
#endif

    float c = init_cov[l];
    float Hx0[8], Hx1[8], Fix[8], Fjx[8], Fjc[8];
#pragma unroll
    for (int e = 0; e < 8; ++e) {
      const int k = i ^ e;
      Hx0[e] = H[k];
      Hx1[e] = H[8 + k];
      Fix[e] = F[i * 8 + k];
      Fjx[e] = F[j * 8 + k];
      Fjc[e] = F[j * 8 + (j ^ e)];
    }
    const float h0j = H[j], h1j = H[8 + j];
    const float qc  = Q[l];
    const float Fij = F[i * 8 + j];
    const float r00 = R[0], r01 = R[1], r11 = R[3];

    float* __restrict__ covs0 = out + OUT_COVS;   // g=0 slot: [T][64]
    const int axaddr = (i << 3) + (i ^ j);

    float aL = 0.f, b0L = 0.f, b1L = 0.f;
    int tconv = T_;

    for (int t = 0; t < T_; ++t) {
      covs0[t * 64 + l] = c;

      float u0 = rowsum8(c * h0j);
      float u1 = rowsum8(c * h1j);

      float ue0[8], ue1[8], ce[8];
      ROWVAR(ue0, u0);
      ROWVAR(ue1, u1);
      ROWVAR(ce,  c);

      float s00, s01, s11;
      DOT8(s00, Hx0, ue0); s00 += r00;
      DOT8(s01, Hx0, ue1); s01 += r01;
      DOT8(s11, Hx1, ue1); s11 += r11;
      float det = s00 * s11 - s01 * s01;
      float rd = __builtin_amdgcn_rcpf(det);
      rd = rd * (2.0f - det * rd);
      rd = rd * (2.0f - det * rd);
      const float i00 = s11 * rd, i01 = -s01 * rd, i11 = s00 * rd;

      float g0, g1, W;
      DOT8(g0, Fix, ue0);
      DOT8(g1, Fix, ue1);
      DOT8(W,  Fix, ce);
      const float b0 = fmaf(g0, i00, g1 * i01);
      const float b1 = fmaf(g0, i01, g1 * i11);

      float bu[8];
#pragma unroll
      for (int e = 0; e < 8; ++e) bu[e] = fmaf(b0, ue0[e], b1 * ue1[e]);
      float bGt;
      DOT8(bGt, Fjx, bu);

      float wv[8];
      wv[0] = W;
      wv[1] = dmov<QP1>(W);
      wv[2] = dmov<QP2>(W);
      wv[3] = dmov<QP1>(wv[2]);
      wv[7] = dmov<HM>(W);
      wv[6] = dmov<HM>(wv[1]);
      wv[5] = dmov<HM>(wv[2]);
      wv[4] = dmov<HM>(wv[3]);
      float fcf;
      DOT8(fcf, Fjc, wv);

      const float cn = fcf + qc - bGt;
      const float A  = Fij - fmaf(b0, h0j, b1 * h1j);

      ab[t * 80 + axaddr] = A;
      if (j == 0) { ab[t * 80 + 64 + i] = b0; ab[t * 80 + 72 + i] = b1; }
      aL = A; b0L = b0; b1L = b1;

      const float d = fabsf(cn - c);
      c = cn;
      if ((t & 3) == 3 && t >= 24) {
        if (__all(d < 2e-4f)) { tconv = t + 1; break; }
      }
    }
    for (int tt = tconv; tt < T_; ++tt) {
      covs0[tt * 64 + l] = c;
      ab[tt * 80 + axaddr] = aL;
      if (j == 0) { ab[tt * 80 + 64 + i] = b0L; ab[tt * 80 + 72 + i] = b1L; }
    }
    // release: all prior stores of this wave are program-ordered before this
    if (l == 0)
      __hip_atomic_store(flag, MAGIC, __ATOMIC_RELEASE, __HIP_MEMORY_SCOPE_AGENT);
    return;
  }

  if (bid <= 64) {
    // ---- phase 1: Rs fill (independent of Riccati) ----
    const f4 rv = ((const f4*)R)[0];
    f4* __restrict__ outRs = (f4*)(out + OUT_RS);
    for (int v = (bid - 1) * 256 + threadIdx.x; v < G_ * T_; v += 64 * 256)
      __builtin_nontemporal_store(rv, &outRs[v]);

    wait_flag(flag);

    // ---- phase 2: mean scan, 8 lanes per group ----
    const int s = threadIdx.x & 7;
    const int g = (bid - 1) * 32 + (threadIdx.x >> 3);

    const float* __restrict__ abf = ab;           // [T][80], A in XOR layout
    const f4* __restrict__ abf4 = (const f4*)abf;
    const float2* __restrict__ inp2 = (const float2*)input;
    float* __restrict__ outm = out + OUT_MEANS;

    float m = init_mean[g * 8 + s];

    f4 a0 = abf4[s * 2], a1 = abf4[s * 2 + 1];
    float b0 = abf[64 + s], b1 = abf[72 + s];
    float2 y = inp2[g * T_];

    for (int t = 0; t < T_; ++t) {
      const int tn = (t + 1 < T_) ? t + 1 : t;
      const f4 a0n = abf4[tn * 20 + s * 2];
      const f4 a1n = abf4[tn * 20 + s * 2 + 1];
      const float b0n = abf[tn * 80 + 64 + s];
      const float b1n = abf[tn * 80 + 72 + s];
      const float2 yn = inp2[g * T_ + tn];

      outm[g * (T_ * 8) + t * 8 + s] = m;

      const float M1 = dmov<QP1>(m);
      const float M2 = dmov<QP2>(m);
      const float M3 = dmov<QP1>(M2);
      const float M7 = dmov<HM>(m);
      const float M6 = dmov<HM>(M1);
      const float M5 = dmov<HM>(M2);
      const float M4 = dmov<HM>(M3);

      const float p0 = fmaf(a0.x, m,  a0.y * M1);
      const float p1 = fmaf(a0.z, M2, a0.w * M3);
      const float p2 = fmaf(a1.x, M4, a1.y * M5);
      const float p3 = fmaf(a1.z, M6, a1.w * M7);
      const float py = fmaf(b0, y.x, b1 * y.y);
      m = ((p0 + p1) + (p2 + p3)) + py;

      a0 = a0n; a1 = a1n; b0 = b0n; b1 = b1n; y = yn;
    }
  } else {
    // ---- phase 1: Hs fill (independent of Riccati) ----
    const f4 hv = ((const f4*)H)[threadIdx.x & 3];  // stride % 4 == 0
    f4* __restrict__ outHs = (f4*)(out + OUT_HS);
    for (int v = (bid - 65) * 256 + threadIdx.x; v < G_ * T_ * 4; v += 962 * 256)
      __builtin_nontemporal_store(hv, &outHs[v]);

    wait_flag(flag);

    // ---- phase 2: covs broadcast fill for g = 1..2047 ----
    const int fb  = bid - 65;            // 0..961 = 13 t-chunks x 74 g-slices
    const int t16 = fb % 13;
    const int gsl = fb / 13;
    const int t   = t16 * 16 + (threadIdx.x >> 4);
    const int e4  = threadIdx.x & 15;
    if (t < T_) {
      const f4* __restrict__ cov4 = (const f4*)(out + OUT_COVS); // g=0 slot
      f4* __restrict__ outc = (f4*)(out + OUT_COVS);
      const f4 val = cov4[t * 16 + e4];
#pragma unroll 4
      for (int k = 0; k < 28; ++k) {
        const int g = 1 + gsl * 28 + k;
        if (g < G_)
          __builtin_nontemporal_store(val, &outc[(g * T_ + t) * 16 + e4]);
      }
    }
  }
}

extern "C" void kernel_launch(void* const* d_in, const int* in_sizes, int n_in,
                              void* d_out, int out_size, void* d_ws, size_t ws_size,
                              hipStream_t stream) {
  const float* input     = (const float*)d_in[0];
  const float* F         = (const float*)d_in[1];
  const float* H         = (const float*)d_in[2];
  const float* Q         = (const float*)d_in[3];
  const float* R         = (const float*)d_in[4];
  const float* init_mean = (const float*)d_in[5];
  const float* init_cov  = (const float*)d_in[6];
  float* out = (float*)d_out;
  float* ws  = (float*)d_ws;

  kfused<<<1027, 256, 0, stream>>>(input, F, H, Q, R, init_mean, init_cov,
                                   out, ws);
}

// Round 11
// 60.886 us; speedup vs baseline: 2.3038x; 1.2606x over previous
//
#include <hip/hip_runtime.h>

#define G_ 2048
#define T_ 200

// Output layout (float offsets)
#define OUT_MEANS 0
#define OUT_COVS  3276800     // G*T*S
#define OUT_RS    29491200    // + G*T*S*S
#define OUT_HS    31129600    // + G*T*M*M

// Workspace layout (float offsets)
#define WS_K    0             // [T][16]: K[s][0] at t*16+s, K[s][1] at t*16+8+s
#define WS_FLAG 3456
#define MAGIC   0x5CA1AB1Eu

typedef float f4 __attribute__((ext_vector_type(4)));

// DPP lane permutes (VALU pipe)
#define QP1  0xB1   // lane^1
#define QP2  0x4E   // lane^2
#define HM   0x141  // lane^7 (row_half_mirror)
#define ROR8 0x128  // lane^8 (row_ror:8)

template<int CTRL>
__device__ __forceinline__ float dmov(float x) {
  return __int_as_float(__builtin_amdgcn_update_dpp(
      0, __float_as_int(x), CTRL, 0xF, 0xF, true));
}
template<int OFF>
__device__ __forceinline__ float swzf(float x) {
  return __int_as_float(__builtin_amdgcn_ds_swizzle(__float_as_int(x), OFF));
}

#if __has_builtin(__builtin_amdgcn_permlane16_swap)
#define HAS_PL16 1
#else
#define HAS_PL16 0
#endif
#if __has_builtin(__builtin_amdgcn_permlane32_swap)
#define HAS_PL32 1
#else
#define HAS_PL32 0
#endif

// ---- select-free cross-half SUMS: {r0,r1} = {x[l], x[l^k]} per lane under
// either swap convention, so r0+r1 = x + x[l^k] always. Pure VALU.
__device__ __forceinline__ float sum16p(float x) {
#if HAS_PL16
  auto r = __builtin_amdgcn_permlane16_swap(__float_as_int(x), __float_as_int(x),
                                            false, false);
  return __int_as_float((int)r[0]) + __int_as_float((int)r[1]);
#else
  return x + swzf<0x401F>(x);
#endif
}
__device__ __forceinline__ float sum32p(float x) {
#if HAS_PL32
  auto r = __builtin_amdgcn_permlane32_swap(__float_as_int(x), __float_as_int(x),
                                            false, false);
  return __int_as_float((int)r[0]) + __int_as_float((int)r[1]);
#else
  return x + __shfl_xor(x, 32, 64);
#endif
}

// ---- gather variants (need exact value: probe-corrected select)
__device__ __forceinline__ float xor16f(float x, int l, bool flip) {
#if HAS_PL16
  auto r = __builtin_amdgcn_permlane16_swap(__float_as_int(x), __float_as_int(x),
                                            false, false);
  const bool sel = (((l & 16) != 0) != flip);
  return __int_as_float(sel ? (int)r[0] : (int)r[1]);
#else
  (void)l; (void)flip;
  return swzf<0x401F>(x);
#endif
}
__device__ __forceinline__ float xor32f(float x, int l, bool flip) {
#if HAS_PL32
  auto r = __builtin_amdgcn_permlane32_swap(__float_as_int(x), __float_as_int(x),
                                            false, false);
  const bool sel = (((l & 32) != 0) != flip);
  return __int_as_float(sel ? (int)r[0] : (int)r[1]);
#else
  (void)l; (void)flip;
  return __shfl_xor(x, 32, 64);
#endif
}

// sum over the 8 lanes of a row (bits 0-2), replicated — all-DPP
__device__ __forceinline__ float rowsum8(float x) {
  x += dmov<QP1>(x); x += dmov<QP2>(x); x += dmov<HM>(x); return x;
}
// sum over the row index (bits 3-5), replicated — DPP + permlane sums
__device__ __forceinline__ float colsum8(float x) {
  x += dmov<ROR8>(x);
  x = sum16p(x);
  x = sum32p(x);
  return x;
}

__device__ __forceinline__ void wait_flag(const unsigned* flag) {
  if (threadIdx.x == 0) {
    while (__hip_atomic_load(flag, __ATOMIC_ACQUIRE,
                             __HIP_MEMORY_SCOPE_AGENT) != MAGIC)
      __builtin_amdgcn_s_sleep(2);
  }
  __syncthreads();
}

// ---------------------------------------------------------------------------
// Fused kernel:
//   block 0       : K-form Riccati (covs -> out g=0 slot, K -> ws), flag
//   blocks 1-64   : Rs fill, wait, mean scan m' = F(m - K(Hm - y))
//   blocks 65-1026: Hs fill, wait, covs broadcast fill (g=1..2047)
// ---------------------------------------------------------------------------
__global__ void __launch_bounds__(256, 1) kfused(
    const float* __restrict__ input, const float* __restrict__ F,
    const float* __restrict__ H, const float* __restrict__ Q,
    const float* __restrict__ R, const float* __restrict__ init_mean,
    const float* __restrict__ init_cov, float* __restrict__ out,
    float* __restrict__ ws)
{
  const int bid = blockIdx.x;
  float* __restrict__ wsk = ws + WS_K;
  unsigned* flag = (unsigned*)(ws + WS_FLAG);

  if (bid == 0) {
    if (threadIdx.x >= 64) return;
    const int l = threadIdx.x;
    const int i = l >> 3, j = l & 7;

    bool flip16 = false, flip32 = false;
#if HAS_PL16
    { auto pr = __builtin_amdgcn_permlane16_swap(l, l, false, false);
      const int got = (l & 16) ? (int)pr[0] : (int)pr[1];
      flip16 = (got != (l ^ 16)); }
#endif
#if HAS_PL32
    { auto pr = __builtin_amdgcn_permlane32_swap(l, l, false, false);
      const int got = (l & 32) ? (int)pr[0] : (int)pr[1];
      flip32 = (got != (l ^ 32)); }
#endif

    float c = init_cov[l];                 // cov[i][j], shared across groups
    float Fix[8], Fjc[8];
#pragma unroll
    for (int e = 0; e < 8; ++e) {
      Fix[e] = F[i * 8 + (i ^ e)];         // F[i][i^e]  (row gather coeffs)
      Fjc[e] = F[j * 8 + (j ^ e)];         // F[j][j^e]  (col gather coeffs)
    }
    const float h0i = H[i],     h1i = H[8 + i];
    const float h0j = H[j],     h1j = H[8 + j];
    const float qc  = Q[l];
    const float r00 = R[0], r01 = R[1], r11 = R[3];

    float* __restrict__ covs0 = out + OUT_COVS;  // g=0 slot: [T][64]
    const bool kst = (j < 2);
    const int  kaddr = (j << 3) + i;             // j=0 -> +i, j=1 -> +8+i

    float k0L = 0.f, k1L = 0.f;
    int tconv = T_;

    for (int t = 0; t < T_; ++t) {
      covs0[t * 64 + l] = c;               // emit pre-update covariance

      // v[j][m] = (H c)[m][j], col-replicated (uses symmetry of c)
      const float v0 = colsum8(c * h0i);
      const float v1 = colsum8(c * h1i);
      // u[i][m] = (c H^T)[i][m], row-replicated
      const float u0 = rowsum8(c * h0j);
      const float u1 = rowsum8(c * h1j);

      // S = H c H^T + R (replicated in every lane)
      const float s00 = colsum8(h0i * u0) + r00;
      const float s01 = colsum8(h0i * u1) + r01;
      const float s11 = colsum8(h1i * u1) + r11;
      const float det = s00 * s11 - s01 * s01;
      float rd = __builtin_amdgcn_rcpf(det);
      rd = rd * (2.0f - det * rd);         // one NR step

      // K = u S^{-1} (row-replicated)
      const float k0 = (u0 * s11 - u1 * s01) * rd;
      const float k1 = (u1 * s00 - u0 * s01) * rd;

      // cov_upd = c - K u^T  (lane-local thanks to v)
      const float cu = c - fmaf(k0, v0, k1 * v1);

      // sandwich: cn = F cu F^T + Q
      const float e1 = dmov<ROR8>(cu);
      const float e2 = xor16f(cu, l, flip16);
      const float e3 = dmov<ROR8>(e2);
      const float e4 = xor32f(cu, l, flip32);
      const float e5 = dmov<ROR8>(e4);
      const float e6 = xor16f(e4, l, flip16);
      const float e7 = dmov<ROR8>(e6);
      const float w0_ = fmaf(Fix[0], cu, Fix[1] * e1);
      const float w1_ = fmaf(Fix[2], e2, Fix[3] * e3);
      const float w2_ = fmaf(Fix[4], e4, Fix[5] * e5);
      const float w3_ = fmaf(Fix[6], e6, Fix[7] * e7);
      const float W   = (w0_ + w1_) + (w2_ + w3_);   // (F cu)[i][j]

      const float x1 = dmov<QP1>(W);
      const float x2 = dmov<QP2>(W);
      const float x3 = dmov<QP1>(x2);
      const float x7 = dmov<HM>(W);
      const float x6 = dmov<HM>(x1);
      const float x5 = dmov<HM>(x2);
      const float x4 = dmov<HM>(x3);
      const float f0_ = fmaf(Fjc[0], W,  Fjc[1] * x1);
      const float f1_ = fmaf(Fjc[2], x2, Fjc[3] * x3);
      const float f2_ = fmaf(Fjc[4], x4, Fjc[5] * x5);
      const float f3_ = fmaf(Fjc[6], x6, Fjc[7] * x7);
      const float cn = ((f0_ + f1_) + (f2_ + f3_)) + qc;

      // store K for the scan
      if (kst) wsk[t * 16 + kaddr] = j ? k1 : k0;
      k0L = k0; k1L = k1;

      const float d = fabsf(cn - c);
      c = cn;
      if ((t & 3) == 3 && t >= 40) {
        if (__all(d < 4e-4f)) { tconv = t + 1; break; }
      }
    }
    // steady-state tail fill
    for (int tt = tconv; tt < T_; ++tt) {
      covs0[tt * 64 + l] = c;
      if (kst) wsk[tt * 16 + kaddr] = j ? k1L : k0L;
    }
    if (l == 0)
      __hip_atomic_store(flag, MAGIC, __ATOMIC_RELEASE, __HIP_MEMORY_SCOPE_AGENT);
    return;
  }

  if (bid <= 64) {
    // ---- phase 1: Rs fill (independent of Riccati) ----
    const f4 rv = ((const f4*)R)[0];
    f4* __restrict__ outRs = (f4*)(out + OUT_RS);
    for (int v = (bid - 1) * 256 + threadIdx.x; v < G_ * T_; v += 64 * 256)
      __builtin_nontemporal_store(rv, &outRs[v]);

    wait_flag(flag);

    // ---- phase 2: mean scan, m' = F(m - K(Hm - y)), 8 lanes per group ----
    const int s = threadIdx.x & 7;
    const int g = (bid - 1) * 32 + (threadIdx.x >> 3);

    const float* __restrict__ kf = wsk;            // [T][16]
    const float2* __restrict__ inp2 = (const float2*)input;
    float* __restrict__ outm = out + OUT_MEANS;

    const float h0s = H[s], h1s = H[8 + s];
    float Fsx[8];
#pragma unroll
    for (int e = 0; e < 8; ++e) Fsx[e] = F[s * 8 + (s ^ e)];

    float m = init_mean[g * 8 + s];
    float k0 = kf[s], k1 = kf[8 + s];
    float2 y = inp2[g * T_];

    for (int t = 0; t < T_; ++t) {
      const int tn = (t + 1 < T_) ? t + 1 : t;
      const float k0n = kf[tn * 16 + s];
      const float k1n = kf[tn * 16 + 8 + s];
      const float2 yn = inp2[g * T_ + tn];

      outm[g * (T_ * 8) + t * 8 + s] = m;   // emit pre-update mean

      // Hm (group reduction, all-DPP)
      const float hm0 = rowsum8(m * h0s);
      const float hm1 = rowsum8(m * h1s);
      const float r0 = hm0 - y.x;
      const float r1 = hm1 - y.y;
      const float tt = m - fmaf(k0, r0, k1 * r1);   // updated mean

      // m' = F tt : group-local xor variants of tt, tree dot
      const float t1 = dmov<QP1>(tt);
      const float t2 = dmov<QP2>(tt);
      const float t3 = dmov<QP1>(t2);
      const float t7 = dmov<HM>(tt);
      const float t6 = dmov<HM>(t1);
      const float t5 = dmov<HM>(t2);
      const float t4 = dmov<HM>(t3);
      const float p0 = fmaf(Fsx[0], tt, Fsx[1] * t1);
      const float p1 = fmaf(Fsx[2], t2, Fsx[3] * t3);
      const float p2 = fmaf(Fsx[4], t4, Fsx[5] * t5);
      const float p3 = fmaf(Fsx[6], t6, Fsx[7] * t7);
      m = (p0 + p1) + (p2 + p3);

      k0 = k0n; k1 = k1n; y = yn;
    }
  } else {
    // ---- phase 1: Hs fill (independent of Riccati) ----
    const f4 hv = ((const f4*)H)[threadIdx.x & 3];  // stride % 4 == 0
    f4* __restrict__ outHs = (f4*)(out + OUT_HS);
    for (int v = (bid - 65) * 256 + threadIdx.x; v < G_ * T_ * 4; v += 962 * 256)
      __builtin_nontemporal_store(hv, &outHs[v]);

    wait_flag(flag);

    // ---- phase 2: covs broadcast fill for g = 1..2047 ----
    const int fb  = bid - 65;            // 0..961 = 13 t-chunks x 74 g-slices
    const int t16 = fb % 13;
    const int gsl = fb / 13;
    const int t   = t16 * 16 + (threadIdx.x >> 4);
    const int e4  = threadIdx.x & 15;
    if (t < T_) {
      const f4* __restrict__ cov4 = (const f4*)(out + OUT_COVS); // g=0 slot
      f4* __restrict__ outc = (f4*)(out + OUT_COVS);
      const f4 val = cov4[t * 16 + e4];
#pragma unroll 4
      for (int k = 0; k < 28; ++k) {
        const int g = 1 + gsl * 28 + k;
        if (g < G_)
          __builtin_nontemporal_store(val, &outc[(g * T_ + t) * 16 + e4]);
      }
    }
  }
}

extern "C" void kernel_launch(void* const* d_in, const int* in_sizes, int n_in,
                              void* d_out, int out_size, void* d_ws, size_t ws_size,
                              hipStream_t stream) {
  const float* input     = (const float*)d_in[0];
  const float* F         = (const float*)d_in[1];
  const float* H         = (const float*)d_in[2];
  const float* Q         = (const float*)d_in[3];
  const float* R         = (const float*)d_in[4];
  const float* init_mean = (const float*)d_in[5];
  const float* init_cov  = (const float*)d_in[6];
  float* out = (float*)d_out;
  float* ws  = (float*)d_ws;

  kfused<<<1027, 256, 0, stream>>>(input, F, H, Q, R, init_mean, init_cov,
                                   out, ws);
}